// Round 18
// baseline (134.116 us; speedup 1.0000x reference)
//
#include <hip/hip_runtime.h>

typedef __bf16 bf16x8 __attribute__((ext_vector_type(8)));
typedef float f32x4 __attribute__((ext_vector_type(4)));

#define TWO_LOG2E 2.88539008177792681f   // 2*log2(e): exp(2x) = exp2(x*TWO_LOG2E)

#define GLOADLDS16(g, l) __builtin_amdgcn_global_load_lds(                     \
    (const __attribute__((address_space(1))) void*)(g),                        \
    (__attribute__((address_space(3))) void*)(l), 16, 0, 0)

__device__ __forceinline__ unsigned f2bf(float f) {
    unsigned u = __float_as_uint(f);
    return (u + 0x7FFFu + ((u >> 16) & 1u)) >> 16;   // RNE
}

// ---------------- kernel 1: row-normalize z=[z1;z2] -> bf16 zn[8192][256] ---------------
__global__ void __launch_bounds__(256) normalize_kernel(
    const float* __restrict__ z1, const float* __restrict__ z2,
    unsigned short* __restrict__ zn, float* __restrict__ S, float* __restrict__ out)
{
    if (blockIdx.x < 32) S[(blockIdx.x << 8) + threadIdx.x] = 0.f;
    if (blockIdx.x == 32 && threadIdx.x == 0) out[0] = 0.f;

    const int wave = threadIdx.x >> 6, lane = threadIdx.x & 63;
    const int row = (blockIdx.x << 2) + wave;               // 2048 blocks * 4 rows
    const float* src = (row < 4096) ? (z1 + row * 256) : (z2 + (row - 4096) * 256);
    float4 v = ((const float4*)src)[lane];                  // 64 lanes * 4 = 256
    float ss = v.x * v.x + v.y * v.y + v.z * v.z + v.w * v.w;
#pragma unroll
    for (int m = 32; m > 0; m >>= 1) ss += __shfl_xor(ss, m, 64);
    float sc = 1.0f / fmaxf(sqrtf(ss), 1e-8f);
    uint2 w;
    w.x = f2bf(v.x * sc) | (f2bf(v.y * sc) << 16);
    w.y = f2bf(v.z * sc) | (f2bf(v.w * sc) << 16);
    *(uint2*)(zn + row * 256 + (lane << 2)) = w;
}

// ---------------- kernel 2: R17 chassis, mirror-cols batched in LDS (FIFO un-poisoned) -
// R17 post-mortem: the autonomous-triangle chassis is right, but per-chunk mirror-col
// atomicAdds share the vmcnt FIFO with global_load_lds -- every 4th interval the
// counted `vmcnt(12)` wait had to drain 2 contended cross-XCD S-line RMWs (~3.7K cyc
// per epilogue, = the entire 2x slowdown; WRITE_SIZE 6.8MB confirmed the storm).
// R18 single change: col-sums go to wave-private LDS colpart[256] (plain ds_write,
// lgkm-only, zero vmcnt pollution; each (cc,ct,n16) written exactly once per job,
// zero-initialized so straddle-skipped chunks contribute 0), flushed as 4 atomic
// instructions per wave AFTER the full vmcnt(0) drain -- off the critical path,
// draining as the wave exits. Everything else = R17 verbatim (passed, absmax 0.0):
// job = 64 rows x 256 cols, keep (r,c2) iff r<=4c2+3; straddle jobs skip cc<2k and
// element-mask cc in {2k,2k+1} (col>=row rowsum / col>row colsum); 2112 jobs reversed
// so short straddle jobs are the tail; stage depth-3 vmcnt(12), drain 12->8->4->0;
// 128B-contiguous stages, XOR swizzle, no barriers anywhere.
__global__ void __launch_bounds__(64, 2) simexp_kernel(
    const unsigned short* __restrict__ zn, float* __restrict__ S)
{
    __shared__ __align__(16) unsigned short Bs[4][2048];    // wave-private 16KB ring
    __shared__ __align__(16) float colpart[256];            // per-job mirror-col sums

    const int lane = threadIdx.x;
    const int q = lane >> 4, n16 = lane & 15;

    const int job = 2111 - blockIdx.x;          // reverse: short straddle jobs last
    int c2 = 0, rem = job;
    while (rem >= (c2 << 2) + 4) { rem -= (c2 << 2) + 4; ++c2; }   // <=32 iters, uniform
    const int r = rem;                          // row-strip 0..4*c2+3
    const int k = r - (c2 << 2);                // >=0 iff diagonal-straddle
    const bool straddle = (k >= 0);
    const int cc0 = straddle ? (k << 1) : 0;    // first computed col-chunk
    const int rowBase = r << 6;
    const int colRun  = c2 << 8;

    *(f32x4*)&colpart[lane << 2] = (f32x4){0.f, 0.f, 0.f, 0.f};   // zero-init (own wave)

    // A: 64 rows x K=256 in registers (frag: row=n16, k=q*8 within 32-elem step)
    bf16x8 a[4][8];
#pragma unroll
    for (int rt = 0; rt < 4; ++rt)
#pragma unroll
        for (int ks = 0; ks < 8; ++ks)
            a[rt][ks] = *(const bf16x8*)(zn + ((rowBase + (rt << 4) + n16) << 8)
                                            + (ks << 5) + (q << 3));

    // stage chunk m (col-chunk m>>2, k-chunk m&3) into ring buffer m&3
    auto stage = [&](int m) {
        const int colBase = colRun + ((m >> 2) << 5);
        const int koff = (m & 3) << 6;
        unsigned short* base = &Bs[m & 3][0];
#pragma unroll
        for (int p = 0; p < 4; ++p) {
            int s = (p << 6) + lane;            // 16B slot 0..255
            int c = s >> 3, d = s & 7;          // 8 consecutive lanes per row -> 128B
            int k8 = d ^ (c & 7);               // XOR swizzle (conflict-free b128 reads)
            GLOADLDS16(zn + ((colBase + c) << 8) + koff + (k8 << 3), base + (s << 3));
        }
    };

    float rs[4][4];
#pragma unroll
    for (int i = 0; i < 4; ++i)
#pragma unroll
        for (int j = 0; j < 4; ++j) rs[i][j] = 0.f;

    f32x4 acc[4][2];
    auto consume = [&](int kc) {                // buffer kc (m&3==kc since m=cc*4+kc)
        const unsigned short* bb = &Bs[kc][0];
#pragma unroll
        for (int ks = 0; ks < 2; ++ks) {
            bf16x8 bf[2];
#pragma unroll
            for (int ct = 0; ct < 2; ++ct) {
                int c  = (ct << 4) + n16;               // col 0..31
                int k8 = ((ks << 2) + q) ^ (c & 7);     // swizzled chunk
                bf[ct] = *(const bf16x8*)(bb + (((c << 3) + k8) << 3));
            }
#pragma unroll
            for (int rt = 0; rt < 4; ++rt)
#pragma unroll
                for (int ct = 0; ct < 2; ++ct)
                    acc[rt][ct] = __builtin_amdgcn_mfma_f32_16x16x32_bf16(
                        a[rt][(kc << 1) + ks], bf[ct], acc[rt][ct], 0, 0, 0);
        }
    };
    auto zacc = [&]() {
#pragma unroll
        for (int rt = 0; rt < 4; ++rt)
#pragma unroll
            for (int ct = 0; ct < 2; ++ct) acc[rt][ct] = (f32x4){0.f, 0.f, 0.f, 0.f};
    };
    // epilogue: rows -> rs (col>=row when masked); mirror cols -> q-reduce + LDS store
    // (col>row when masked). NO vmem ops here -- keeps the staging FIFO clean.
    auto epiC = [&](int cc, bool msk) {
        float cs[2] = {0.f, 0.f};
        const int colC = colRun + (cc << 5);
#pragma unroll
        for (int rt = 0; rt < 4; ++rt)
#pragma unroll
            for (int ct = 0; ct < 2; ++ct) {
                const int col = colC + (ct << 4) + n16;
                const int rw0 = rowBase + (rt << 4) + (q << 2);
#pragma unroll
                for (int rr = 0; rr < 4; ++rr) {
                    float e = __builtin_amdgcn_exp2f(acc[rt][ct][rr] * TWO_LOG2E);
                    if (msk) {
                        int row = rw0 + rr;
                        rs[rt][rr] += (col >= row) ? e : 0.f;
                        cs[ct]     += (col >  row) ? e : 0.f;
                    } else {
                        rs[rt][rr] += e;
                        cs[ct] += e;
                    }
                }
            }
#pragma unroll
        for (int ct = 0; ct < 2; ++ct) {
            float s = cs[ct];
            s += __shfl_xor(s, 16, 64);         // reduce over q
            s += __shfl_xor(s, 32, 64);
            if (lane < 16) colpart[(cc << 5) + (ct << 4) + n16] = s;  // once per (cc,ct)
        }
    };

    // prologue: depth-3 (chunks m0, m0+1, m0+2; m0 = cc0*4 so buffers 0,1,2)
    const int m0 = cc0 << 2;
    stage(m0); stage(m0 + 1); stage(m0 + 2);

    for (int cc = cc0; cc < 7; ++cc) {          // intervals m=cc*4+kc, m=m0..27
        zacc();
        const bool msk = straddle && (cc < (k << 1) + 2);   // wave-uniform
#pragma unroll
        for (int kc = 0; kc < 4; ++kc) {
            stage((cc << 2) + kc + 3);          // stages m0+3..30
            asm volatile("s_waitcnt vmcnt(12)" ::: "memory");  // chunk m complete
            consume(kc);
        }
        epiC(cc, msk);
    }
    // peeled tail cc=7: chunks 28..31 (stage 31 then drain 12->8->4->0)
    zacc();
    stage(31);
    asm volatile("s_waitcnt vmcnt(12)" ::: "memory");
    consume(0);
    asm volatile("s_waitcnt vmcnt(8)" ::: "memory");
    consume(1);
    asm volatile("s_waitcnt vmcnt(4)" ::: "memory");
    consume(2);
    asm volatile("s_waitcnt vmcnt(0)" ::: "memory");
    consume(3);
    epiC(7, straddle && (7 < (k << 1) + 2));    // masked only for k=3

    // row flush (C/D layout: col=n16, row=q*4+r); wave covers 64 rows
#pragma unroll
    for (int rt = 0; rt < 4; ++rt)
#pragma unroll
        for (int rr = 0; rr < 4; ++rr) {
            float s = rs[rt][rr];
            s += __shfl_xor(s, 1, 64);
            s += __shfl_xor(s, 2, 64);
            s += __shfl_xor(s, 4, 64);
            s += __shfl_xor(s, 8, 64);
            if (n16 == 0) atomicAdd(&S[rowBase + (rt << 4) + (q << 2) + rr], s);
        }

    // mirror-col flush: batched, AFTER the full drain -- atomics retire as the wave
    // exits, never blocking the MFMA pipeline. Skipped chunks contribute +0.0.
    {
        f32x4 v = *(const f32x4*)&colpart[lane << 2];
#pragma unroll
        for (int i = 0; i < 4; ++i)
            atomicAdd(&S[colRun + (lane << 2) + i], v[i]);
    }
}

// ---------------- kernel 3: loss = mean( log(S_i - e^{sim_ii}) - sim_{i,target} ) -------
__global__ void __launch_bounds__(256) finish_kernel(
    const unsigned short* __restrict__ zn, const float* __restrict__ S,
    float* __restrict__ out)
{
    __shared__ float vals[16];
    const int tid = threadIdx.x, lane = tid & 63, wave = tid >> 6;
    const int q = lane >> 4, n16 = lane & 15;
    const int rib = (wave << 2) + q;                // 0..15 rows per block
    const int row = (blockIdx.x << 4) + rib;        // 512 blocks * 16 rows
    const int tar = (row + 4096) & 8191;

    float drr = 0.f, drt = 0.f;
#pragma unroll
    for (int i = 0; i < 4; ++i) {
        int k = (i << 6) + (n16 << 2);
        uint2 ur = *(const uint2*)(zn + (row << 8) + k);
        uint2 ut = *(const uint2*)(zn + (tar << 8) + k);
        float a0 = __uint_as_float(ur.x << 16),  a1 = __uint_as_float(ur.x & 0xFFFF0000u);
        float a2 = __uint_as_float(ur.y << 16),  a3 = __uint_as_float(ur.y & 0xFFFF0000u);
        float b0 = __uint_as_float(ut.x << 16),  b1 = __uint_as_float(ut.x & 0xFFFF0000u);
        float b2 = __uint_as_float(ut.y << 16),  b3 = __uint_as_float(ut.y & 0xFFFF0000u);
        drr += a0 * a0 + a1 * a1 + a2 * a2 + a3 * a3;
        drt += a0 * b0 + a1 * b1 + a2 * b2 + a3 * b3;
    }
#pragma unroll
    for (int m = 1; m <= 8; m <<= 1) {
        drr += __shfl_xor(drr, m, 64);
        drt += __shfl_xor(drt, m, 64);
    }
    if (n16 == 0) {
        float Sv = S[row] - __builtin_amdgcn_exp2f(drr * TWO_LOG2E);  // remove diagonal
        vals[rib] = 0.693147180559945f * __builtin_amdgcn_logf(Sv) - 2.0f * drt;
    }
    __syncthreads();
    if (tid == 0) {
        float s = 0.f;
#pragma unroll
        for (int i = 0; i < 16; ++i) s += vals[i];
        atomicAdd(out, s * (1.0f / 8192.0f));
    }
}

extern "C" void kernel_launch(void* const* d_in, const int* in_sizes, int n_in,
                              void* d_out, int out_size, void* d_ws, size_t ws_size,
                              hipStream_t stream)
{
    const float* z1 = (const float*)d_in[0];
    const float* z2 = (const float*)d_in[1];
    unsigned short* zn = (unsigned short*)d_ws;                              // 4 MB
    float* S = (float*)((char*)d_ws + 8192 * 256 * sizeof(unsigned short));  // 32 KB
    float* out = (float*)d_out;

    normalize_kernel<<<2048, 256, 0, stream>>>(z1, z2, zn, S, out);
    simexp_kernel<<<2112, 64, 0, stream>>>(zn, S);
    finish_kernel<<<512, 256, 0, stream>>>(zn, S, out);
}

// Round 19
// 101.714 us; speedup vs baseline: 1.3186x; 1.3186x over previous
//
#include <hip/hip_runtime.h>

typedef __bf16 bf16x8 __attribute__((ext_vector_type(8)));
typedef float f32x4 __attribute__((ext_vector_type(4)));

#define TWO_LOG2E 2.88539008177792681f   // 2*log2(e): exp(2x) = exp2(x*TWO_LOG2E)

#define GLOADLDS16(g, l) __builtin_amdgcn_global_load_lds(                     \
    (const __attribute__((address_space(1))) void*)(g),                        \
    (__attribute__((address_space(3))) void*)(l), 16, 0, 0)

__device__ __forceinline__ unsigned f2bf(float f) {
    unsigned u = __float_as_uint(f);
    return (u + 0x7FFFu + ((u >> 16) & 1u)) >> 16;   // RNE
}

// ---------------- kernel 1: row-normalize z=[z1;z2] -> bf16 zn[8192][256] ---------------
__global__ void __launch_bounds__(256) normalize_kernel(
    const float* __restrict__ z1, const float* __restrict__ z2,
    unsigned short* __restrict__ zn, float* __restrict__ S, float* __restrict__ out)
{
    if (blockIdx.x < 32) S[(blockIdx.x << 8) + threadIdx.x] = 0.f;
    if (blockIdx.x == 32 && threadIdx.x == 0) out[0] = 0.f;

    const int wave = threadIdx.x >> 6, lane = threadIdx.x & 63;
    const int row = (blockIdx.x << 2) + wave;               // 2048 blocks * 4 rows
    const float* src = (row < 4096) ? (z1 + row * 256) : (z2 + (row - 4096) * 256);
    float4 v = ((const float4*)src)[lane];                  // 64 lanes * 4 = 256
    float ss = v.x * v.x + v.y * v.y + v.z * v.z + v.w * v.w;
#pragma unroll
    for (int m = 32; m > 0; m >>= 1) ss += __shfl_xor(ss, m, 64);
    float sc = 1.0f / fmaxf(sqrtf(ss), 1e-8f);
    uint2 w;
    w.x = f2bf(v.x * sc) | (f2bf(v.y * sc) << 16);
    w.y = f2bf(v.z * sc) | (f2bf(v.w * sc) << 16);
    *(uint2*)(zn + row * 256 + (lane << 2)) = w;
}

// ---------------- kernel 2: symmetric triangle, ONE uniform proven body ----------------
// FINAL (R19 = R8 verbatim, best measured 100.49us, absmax 0.0). All 528 upper-triangle
// tiles (496 off-diag + 32 diag) are identical 32-interval lockstep blocks:
//   parity staging (group g=wv>>2 stages parity-g chunks, 128B-contiguous rows, XOR
//   swizzle), ring-4 depth-2, counted `s_waitcnt vmcnt(1)`, raw s_barrier publish.
//   NEVER __syncthreads mid-loop (drains vmcnt).
// Off-diag (ti<tj): rows -> rs (atomic flush), cols -> colpart LDS, cross-wave reduce,
//   ONE atomic per column (320 atomics/block).
// Diag (ti==tj): row path ONLY -- a fully computed diag tile contains both orderings
//   of every pair, so row-sums cover it; self-sim included, finish subtracts it.
// Ceiling evidence (R1-R18): per-chunk interval = 2760cy vs ~1900cy component floor;
// the residual is invariant under traffic volume (R4), XCD locality (R9), occupancy
// (R1), instruction pressure / LDS-per-MFMA (R11), sync cadence (R12), prefetch depth
// (R14), A-residency (R15), and wave autonomy (R17/18). Symmetry-halving chassis all
// regress via mirror-scatter cost (R6 +7us, R17 +13us, R18 +33us).
__global__ void __launch_bounds__(512, 4) simexp_kernel(
    const unsigned short* __restrict__ zn, float* __restrict__ S)
{
    __shared__ __align__(16) unsigned short Bs[4][2048];    // 4 x 4KB ring
    __shared__ float colpart[8][256];                       // per-wave col partials

    const int tid = threadIdx.x;
    const int wv = tid >> 6, lane = tid & 63;
    const int q = lane >> 4, n16 = lane & 15;
    const int g = wv >> 2, wl = wv & 3;         // staging group / quarter within group
    const int job = blockIdx.x;                 // 0..527

    int ti, tj;
    bool diag;
    if (job >= 496) {                           // diagonal tile
        ti = tj = job - 496;
        diag = true;
    } else {                                    // off-diag tile, ti<tj
        int t = 0, rem = job;
        while (rem >= 31 - t) { rem -= 31 - t; ++t; }   // uniform scan, <=31 iters
        ti = t; tj = t + 1 + rem;
        diag = false;
    }
    const int colTile = tj << 8;
    const int rowW = (ti << 8) + (wv << 5);     // this wave's 32 rows

    // A: 32 rows x K=256 in registers (frag: row=n16, k=q*8 within 32-elem step)
    bf16x8 a[2][8];
#pragma unroll
    for (int rt = 0; rt < 2; ++rt)
#pragma unroll
        for (int ks = 0; ks < 8; ++ks)
            a[rt][ks] = *(const bf16x8*)(zn + ((rowW + (rt << 4) + n16) << 8)
                                            + (ks << 5) + (q << 3));

    auto stage = [&](int m) {                   // 128B-contiguous rows (R3/R7 lesson)
        const int colBase = colTile + ((m >> 2) << 5);
        const int koff = (m & 3) << 6;
        unsigned short* base = &Bs[m & 3][0];
        int s = (wl << 6) + lane;               // 16B slot 0..255
        int c = s >> 3, d = s & 7;              // 8 consecutive lanes per row -> 128B
        int k8 = d ^ (c & 7);                   // XOR swizzle (conflict-free b128 reads)
        GLOADLDS16(zn + ((colBase + c) << 8) + koff + (k8 << 3), base + (s << 3));
    };

    float rs[2][4];
#pragma unroll
    for (int i = 0; i < 2; ++i)
#pragma unroll
        for (int j = 0; j < 4; ++j) rs[i][j] = 0.f;

    f32x4 acc[2][2];
    auto consume = [&](int kc) {                // buffer kc (m&3==kc since m=cc*4+kc)
        const unsigned short* bb = &Bs[kc & 3][0];
#pragma unroll
        for (int ks = 0; ks < 2; ++ks) {
            bf16x8 bf[2];
#pragma unroll
            for (int ct = 0; ct < 2; ++ct) {
                int c  = (ct << 4) + n16;               // col 0..31
                int k8 = ((ks << 2) + q) ^ (c & 7);     // swizzled chunk
                bf[ct] = *(const bf16x8*)(bb + (((c << 3) + k8) << 3));
            }
#pragma unroll
            for (int rt = 0; rt < 2; ++rt)
#pragma unroll
                for (int ct = 0; ct < 2; ++ct)
                    acc[rt][ct] = __builtin_amdgcn_mfma_f32_16x16x32_bf16(
                        a[rt][(kc << 1) + ks], bf[ct], acc[rt][ct], 0, 0, 0);
        }
    };
    auto zacc = [&]() {
#pragma unroll
        for (int rt = 0; rt < 2; ++rt)
#pragma unroll
            for (int ct = 0; ct < 2; ++ct) acc[rt][ct] = (f32x4){0.f, 0.f, 0.f, 0.f};
    };
    auto epiC = [&](int cc) {                   // rows -> rs; cols -> colpart (off-diag)
        float cs[2] = {0.f, 0.f};
#pragma unroll
        for (int rt = 0; rt < 2; ++rt)
#pragma unroll
            for (int ct = 0; ct < 2; ++ct)
#pragma unroll
                for (int r = 0; r < 4; ++r) {
                    float e = __builtin_amdgcn_exp2f(acc[rt][ct][r] * TWO_LOG2E);
                    rs[rt][r] += e;
                    cs[ct] += e;
                }
        if (!diag) {                            // wave-uniform
#pragma unroll
            for (int ct = 0; ct < 2; ++ct) {
                float s = cs[ct];
                s += __shfl_xor(s, 16, 64);     // reduce over q
                s += __shfl_xor(s, 32, 64);
                if (lane < 16) colpart[wv][(cc << 5) + (ct << 4) + n16] = s;
            }
        }
    };

    if (g == 0) stage(0); else stage(1);        // prologue, parity-consistent

    for (int cc = 0; cc < 7; ++cc) {            // intervals m=cc*4+kc, m=0..27
        zacc();
#pragma unroll
        for (int kc = 0; kc < 4; ++kc) {
            if ((kc & 1) == g) {                // wave-uniform branch
                stage((cc << 2) + kc + 2);
                asm volatile("s_waitcnt vmcnt(1)" ::: "memory");  // own chunk-m done
            }
            __builtin_amdgcn_s_barrier();
            asm volatile("" ::: "memory");      // keep ds_reads below the barrier
            consume(kc);
        }
        epiC(cc);
    }
    // peeled tail cc=7: chunks 28..31 (stage 30 by g0, 31 by g1, then drain)
    zacc();
    if (g == 0) { stage(30); asm volatile("s_waitcnt vmcnt(1)" ::: "memory"); }
    __builtin_amdgcn_s_barrier();
    asm volatile("" ::: "memory");
    consume(0);
    if (g == 1) { stage(31); asm volatile("s_waitcnt vmcnt(1)" ::: "memory"); }
    __builtin_amdgcn_s_barrier();
    asm volatile("" ::: "memory");
    consume(1);
    if (g == 0) { asm volatile("s_waitcnt vmcnt(0)" ::: "memory"); }
    __builtin_amdgcn_s_barrier();
    asm volatile("" ::: "memory");
    consume(2);
    if (g == 1) { asm volatile("s_waitcnt vmcnt(0)" ::: "memory"); }
    __builtin_amdgcn_s_barrier();
    asm volatile("" ::: "memory");
    consume(3);
    epiC(7);

    // row flush (C/D layout: col=n16, row=q*4+r)
#pragma unroll
    for (int rt = 0; rt < 2; ++rt)
#pragma unroll
        for (int r = 0; r < 4; ++r) {
            float s = rs[rt][r];
            s += __shfl_xor(s, 1, 64);
            s += __shfl_xor(s, 2, 64);
            s += __shfl_xor(s, 4, 64);
            s += __shfl_xor(s, 8, 64);
            if (n16 == 0) atomicAdd(&S[rowW + (rt << 4) + (q << 2) + r], s);
        }

    // off-diag only: cross-wave col reduction, ONE atomic per column. vmcnt is fully
    // drained above, so __syncthreads is safe here (also publishes colpart writes).
    if (!diag) {
        __syncthreads();
        if (tid < 256) {
            float s = 0.f;
#pragma unroll
            for (int w = 0; w < 8; ++w) s += colpart[w][tid];
            atomicAdd(&S[colTile + tid], s);
        }
    }
}

// ---------------- kernel 3: loss = mean( log(S_i - e^{sim_ii}) - sim_{i,target} ) -------
__global__ void __launch_bounds__(256) finish_kernel(
    const unsigned short* __restrict__ zn, const float* __restrict__ S,
    float* __restrict__ out)
{
    __shared__ float vals[16];
    const int tid = threadIdx.x, lane = tid & 63, wave = tid >> 6;
    const int q = lane >> 4, n16 = lane & 15;
    const int rib = (wave << 2) + q;                // 0..15 rows per block
    const int row = (blockIdx.x << 4) + rib;        // 512 blocks * 16 rows
    const int tar = (row + 4096) & 8191;

    float drr = 0.f, drt = 0.f;
#pragma unroll
    for (int i = 0; i < 4; ++i) {
        int k = (i << 6) + (n16 << 2);
        uint2 ur = *(const uint2*)(zn + (row << 8) + k);
        uint2 ut = *(const uint2*)(zn + (tar << 8) + k);
        float a0 = __uint_as_float(ur.x << 16),  a1 = __uint_as_float(ur.x & 0xFFFF0000u);
        float a2 = __uint_as_float(ur.y << 16),  a3 = __uint_as_float(ur.y & 0xFFFF0000u);
        float b0 = __uint_as_float(ut.x << 16),  b1 = __uint_as_float(ut.x & 0xFFFF0000u);
        float b2 = __uint_as_float(ut.y << 16),  b3 = __uint_as_float(ut.y & 0xFFFF0000u);
        drr += a0 * a0 + a1 * a1 + a2 * a2 + a3 * a3;
        drt += a0 * b0 + a1 * b1 + a2 * b2 + a3 * b3;
    }
#pragma unroll
    for (int m = 1; m <= 8; m <<= 1) {
        drr += __shfl_xor(drr, m, 64);
        drt += __shfl_xor(drt, m, 64);
    }
    if (n16 == 0) {
        float Sv = S[row] - __builtin_amdgcn_exp2f(drr * TWO_LOG2E);  // remove diagonal
        vals[rib] = 0.693147180559945f * __builtin_amdgcn_logf(Sv) - 2.0f * drt;
    }
    __syncthreads();
    if (tid == 0) {
        float s = 0.f;
#pragma unroll
        for (int i = 0; i < 16; ++i) s += vals[i];
        atomicAdd(out, s * (1.0f / 8192.0f));
    }
}

extern "C" void kernel_launch(void* const* d_in, const int* in_sizes, int n_in,
                              void* d_out, int out_size, void* d_ws, size_t ws_size,
                              hipStream_t stream)
{
    const float* z1 = (const float*)d_in[0];
    const float* z2 = (const float*)d_in[1];
    unsigned short* zn = (unsigned short*)d_ws;                              // 4 MB
    float* S = (float*)((char*)d_ws + 8192 * 256 * sizeof(unsigned short));  // 32 KB
    float* out = (float*)d_out;

    normalize_kernel<<<2048, 256, 0, stream>>>(z1, z2, zn, S, out);
    simexp_kernel<<<528, 512, 0, stream>>>(zn, S);
    finish_kernel<<<512, 256, 0, stream>>>(zn, S, out);
}